// Round 14
// baseline (162.922 us; speedup 1.0000x reference)
//
#include <hip/hip_runtime.h>
#include <hip/hip_bf16.h>

// Sizes (fixed): B=128, M=1024, D_Z=1024, D_PHI=512, H1=512, H2=512
// ws: hzb f32[128*512] @0 (256K) | hpb bf16[1024*512] @256K (1M) |
//     W2F bf16[512*512] @1.25M (512K)
//
// W2F frag layout (16x16x32 B-frags, 1024B contiguous):
//   idx = (kc*32 + nf)*512 + lane*8, lane=(n&15)+16*((k>>3)&3),
//   holds W2[k..k+8][n].
//
// RULES LEARNED:
//  r7:  keep VGPR+AGPR <= 128/thread (4 waves/SIMD) in the big kernel.
//  r8/r9: gelu is VALU-issue-heavy -> packed fp32.
//  r10: NO control-flow duplication around acc. Straight-line bodies only.
//  r11/r12: fused-body restructures all lose; r9 body is the practical floor.
//  r13: extra prep passes/serial deps cost more than they save.
//  r14: ONE prep kernel: W2F-cast blocks + 72 barrier-free l1 blocks reading
//       W1/g_q/Phi f32 directly (no W1F pass, no wcast->l1 serialization).

typedef __bf16 bf16x8 __attribute__((ext_vector_type(8)));
typedef float  f32x4  __attribute__((ext_vector_type(4)));
typedef float  f32x2  __attribute__((ext_vector_type(2)));

// tanh-form GELU, packed pair. exp2(x*(c1 + c3*x^2)) identical to
// exp2(2.3022082*(x + 0.044715 x^3)); c3 = 2.3022082*0.044715.
__device__ __forceinline__ f32x2 gelu_pk(f32x2 x) {
    f32x2 t = x * x;
    f32x2 p = __builtin_elementwise_fma(t, f32x2{0.1029436f, 0.1029436f},
                                        f32x2{2.3022082f, 2.3022082f});
    f32x2 a = p * x;
    f32x2 e;
    e.x = __builtin_amdgcn_exp2f(a.x);
    e.y = __builtin_amdgcn_exp2f(a.y);
    f32x2 d = e + f32x2{1.f, 1.f};
    f32x2 r;
    r.x = __builtin_amdgcn_rcpf(d.x);
    r.y = __builtin_amdgcn_rcpf(d.y);
    return __builtin_elementwise_fma(-x, r, x);   // x - x*r
}

__device__ __forceinline__ unsigned int pack_bf16x2(float a, float b) {
    __hip_bfloat162 h = __float22bfloat162_rn(make_float2(a, b));
    return *reinterpret_cast<unsigned int*>(&h);
}
__device__ __forceinline__ float bf_lo(unsigned int u) {
    return __builtin_bit_cast(float, u << 16);
}
__device__ __forceinline__ float bf_hi(unsigned int u) {
    return __builtin_bit_cast(float, u & 0xffff0000u);
}

// ---------------- prep: W2F cast (64 blocks) + l1 GEMM (72 blocks) ----------------
// grid 136 x 512:
//   [0,64):   W2F transpose-cast 64x64 tiles (LDS staged)
//   [64,72):  hz = g_q @ W1[:1024] + b1 -> f32 hzb   (16r x 512c, K=1024)
//   [72,136): hp = bf16(Phi @ W1[1024:]) -> hpb      (16r x 512c, K=512)
// l1 blocks: barrier-free, no LDS; A from g_q/Phi rows (2xfloat4/lane),
// B gathered from W1 columns (8 dwords/lane, 4x64B segments/instr, L2-hit).
__global__ __launch_bounds__(512) void prep_kernel(
    const float* __restrict__ g_q, const float* __restrict__ Phi,
    const float* __restrict__ W1, const float* __restrict__ b1,
    const float* __restrict__ W2,
    float* __restrict__ hzb, unsigned short* __restrict__ hpb,
    unsigned short* __restrict__ W2F)
{
    __shared__ float tr[64 * 68];   // 17 KB (W2F branch only)
    const int t = threadIdx.x;
    const int id = blockIdx.x;

    if (id < 64) {
        // ----- W2F: transpose-cast one 64x64 tile -----
        const int kt = id >> 3, nt = id & 7;
        const int k0 = kt * 64, n0 = nt * 64;
        {
            int row = t >> 3, col = (t & 7) * 8;
            *(float4*)&tr[row * 68 + col] =
                *(const float4*)&W2[(k0 + row) * 512 + n0 + col];
            *(float4*)&tr[row * 68 + col + 4] =
                *(const float4*)&W2[(k0 + row) * 512 + n0 + col + 4];
        }
        __syncthreads();
        const int nl = t >> 3, kc16 = (t & 7) * 8;
        unsigned int pk[4];
        #pragma unroll
        for (int i = 0; i < 4; ++i) {
            float f0 = tr[(kc16 + 2 * i    ) * 68 + nl];
            float f1 = tr[(kc16 + 2 * i + 1) * 68 + nl];
            pk[i] = pack_bf16x2(f0, f1);
        }
        const int n   = n0 + nl;
        const int nf  = n >> 4;
        const int kbase = k0 + kc16;
        const int kc  = kbase >> 5;
        const int k8  = (kbase >> 3) & 3;
        const int lane = (n & 15) + 16 * k8;
        *(uint4*)&W2F[(unsigned)((kc * 32 + nf) * 512 + lane * 8)] =
            make_uint4(pk[0], pk[1], pk[2], pk[3]);
    } else {
        // ----- l1: 16 rows x 512 cols, barrier-free -----
        const int bi = id - 64;
        const bool is_hz = bi < 8;
        const int r0  = is_hz ? bi * 16 : (bi - 8) * 16;
        const int ld  = is_hz ? 1024 : 512;
        const int nkc = is_hz ? 32 : 16;     // K/32
        const int kw0 = is_hz ? 0 : 1024;    // W1 row base
        const float* src = is_hz ? g_q : Phi;

        const int w = t >> 6;
        const int l = t & 63;
        const int row = r0 + (l & 15);
        const int k8  = l >> 4;
        const float* arow = src + (unsigned)row * ld;

        f32x4 acc[4];
        #pragma unroll
        for (int bf = 0; bf < 4; ++bf) acc[bf] = f32x4{0.f, 0.f, 0.f, 0.f};

        #pragma unroll 2
        for (int kc = 0; kc < nkc; ++kc) {
            const int kb = kc * 32 + k8 * 8;
            // A-frag: lane holds A[row][kb..kb+8)
            float4 a0 = *(const float4*)&arow[kb];
            float4 a1 = *(const float4*)&arow[kb + 4];
            uint4 av;
            av.x = pack_bf16x2(a0.x, a0.y);
            av.y = pack_bf16x2(a0.z, a0.w);
            av.z = pack_bf16x2(a1.x, a1.y);
            av.w = pack_bf16x2(a1.z, a1.w);
            bf16x8 af = __builtin_bit_cast(bf16x8, av);
            // B-frags: lane holds W1[kw0+kb..+8)[n], n = w*64 + bf*16 + (l&15)
            #pragma unroll
            for (int bf = 0; bf < 4; ++bf) {
                const float* wp = &W1[(unsigned)(kw0 + kb) * 512 + w * 64 + bf * 16 + (l & 15)];
                float b0 = wp[0],        b1v = wp[512];
                float b2 = wp[2 * 512],  b3v = wp[3 * 512];
                float b4 = wp[4 * 512],  b5v = wp[5 * 512];
                float b6 = wp[6 * 512],  b7v = wp[7 * 512];
                uint4 bv;
                bv.x = pack_bf16x2(b0, b1v);
                bv.y = pack_bf16x2(b2, b3v);
                bv.z = pack_bf16x2(b4, b5v);
                bv.w = pack_bf16x2(b6, b7v);
                acc[bf] = __builtin_amdgcn_mfma_f32_16x16x32_bf16(
                    af, __builtin_bit_cast(bf16x8, bv), acc[bf], 0, 0, 0);
            }
        }

        // epilogue: C layout col=l&15, row=(l>>4)*4+r within the 16x16 tile
        const int cl = l & 15, rq = (l >> 4) * 4;
        #pragma unroll
        for (int bf = 0; bf < 4; ++bf) {
            int n = w * 64 + bf * 16 + cl;
            if (is_hz) {
                float bb = b1[n];
                #pragma unroll
                for (int r = 0; r < 4; ++r)
                    hzb[(unsigned)(r0 + rq + r) * 512 + n] = acc[bf][r] + bb;
            } else {
                #pragma unroll
                for (int r = 0; r < 4; ++r) {
                    __hip_bfloat16 v = __float2bfloat16(acc[bf][r]);
                    hpb[(unsigned)(r0 + rq + r) * 512 + n] =
                        *reinterpret_cast<unsigned short*>(&v);
                }
            }
        }
    }
}

// ---------------- fused: gelu1 -> bf16 GEMM (x W2) -> gelu2 -> dot W3 ----------------
// r9 verbatim: 64r x 512c, 8 waves, wave 64x64 (acc 4x4), one barrier/kt,
// B frags global->reg, hp via 2x8KB global_load_lds ring, packed gelu.
__global__ __launch_bounds__(512, 2) void fused_kernel(
    const float* __restrict__ hzb, const unsigned short* __restrict__ hpb,
    const unsigned short* __restrict__ W2F,
    const float* __restrict__ b2, const float* __restrict__ W3,
    const float* __restrict__ b3, float* __restrict__ out)
{
    __shared__ __align__(16) unsigned short lA[2 * 64 * 64];      // 16 KB
    __shared__ __align__(16) unsigned short hstage[2 * 64 * 64];  // 16 KB
    __shared__ __align__(16) float lhz[512];
    __shared__ float lred[8][64];

    const int t = threadIdx.x;
    const int w = __builtin_amdgcn_readfirstlane(t >> 6);  // wave id, SGPR
    const int l = t & 63;
    const int r0 = blockIdx.x * 64;
    const int b  = r0 >> 10;
    const int m0 = r0 & 1023;

    f32x4 acc[4][4];
    #pragma unroll
    for (int a = 0; a < 4; ++a)
        #pragma unroll
        for (int bf = 0; bf < 4; ++bf)
            acc[a][bf] = f32x4{0.f, 0.f, 0.f, 0.f};

    const int arow = t >> 3;
    const int ac   = t & 7;
    const unsigned short* hprow = hpb + (unsigned)(m0 + arow) * 512;
    const float4* lhz4 = (const float4*)lhz;
    const unsigned int awoff = (unsigned)(arow * 128 + ((ac ^ (arow & 7)) << 4));
    const unsigned int hoff  = (unsigned)(t * 16);

    auto HPSTAGE = [&](int kt, int buf) {
        __builtin_amdgcn_global_load_lds(
            (const __attribute__((address_space(1))) void*)(hprow + kt * 64 + ac * 8),
            (__attribute__((address_space(3))) void*)((char*)hstage + buf * 8192 + hoff),
            16, 0, 0);
    };

    auto AGEN = [&](int kt, int abuf) {
        uint4 hv = *(const uint4*)((const char*)hstage + (kt & 1) * 8192 + hoff);
        const int kb = kt * 64 + ac * 8;
        float4 z0 = lhz4[kb >> 2];
        float4 z1 = lhz4[(kb >> 2) + 1];
        f32x2 g0 = gelu_pk(f32x2{bf_lo(hv.x), bf_hi(hv.x)} + f32x2{z0.x, z0.y});
        f32x2 g1 = gelu_pk(f32x2{bf_lo(hv.y), bf_hi(hv.y)} + f32x2{z0.z, z0.w});
        f32x2 g2 = gelu_pk(f32x2{bf_lo(hv.z), bf_hi(hv.z)} + f32x2{z1.x, z1.y});
        f32x2 g3 = gelu_pk(f32x2{bf_lo(hv.w), bf_hi(hv.w)} + f32x2{z1.z, z1.w});
        uint4 pk;
        pk.x = pack_bf16x2(g0.x, g0.y);
        pk.y = pack_bf16x2(g1.x, g1.y);
        pk.z = pack_bf16x2(g2.x, g2.y);
        pk.w = pack_bf16x2(g3.x, g3.y);
        *(uint4*)((char*)lA + (unsigned)(abuf * 8192) + awoff) = pk;
    };

    // ---- prologue ----
    HPSTAGE(0, 0);
    HPSTAGE(1, 1);
    lhz[t] = hzb[b * 512 + t];
    __syncthreads();            // vmcnt drain: hstage0/1 + lhz ready
    AGEN(0, 0);
    __syncthreads();            // lA[0] ready

    // ---- main loop: one barrier per kt ----
    #pragma unroll 2
    for (int kt = 0; kt < 8; ++kt) {
        if (kt < 6) HPSTAGE(kt + 2, kt & 1);

        uint4 breg[2][4];
        #pragma unroll
        for (int kk = 0; kk < 2; ++kk)
            #pragma unroll
            for (int bf = 0; bf < 4; ++bf)
                breg[kk][bf] = *(const uint4*)
                    &W2F[(unsigned)(((kt * 2 + kk) * 32 + w * 4 + bf) * 512 + l * 8)];

        if (kt < 7) AGEN(kt + 1, (kt + 1) & 1);

        const char* abase = (const char*)lA + (kt & 1) * 8192;
        #pragma unroll
        for (int kk = 0; kk < 2; ++kk) {
            const int cch = kk * 4 + (l >> 4);
            bf16x8 af[4];
            #pragma unroll
            for (int a = 0; a < 4; ++a) {
                int row = 16 * a + (l & 15);
                unsigned off = (unsigned)(row * 128 + ((cch ^ (row & 7)) << 4));
                af[a] = __builtin_bit_cast(bf16x8, *(const uint4*)(abase + off));
            }
            #pragma unroll
            for (int bf = 0; bf < 4; ++bf) {
                bf16x8 bfr = __builtin_bit_cast(bf16x8, breg[kk][bf]);
                #pragma unroll
                for (int a = 0; a < 4; ++a)
                    acc[a][bf] = __builtin_amdgcn_mfma_f32_16x16x32_bf16(
                        af[a], bfr, acc[a][bf], 0, 0, 0);
            }
        }

        __syncthreads();
    }

    // ---- epilogue: +b2, gelu2 (packed), dot W3, reduce ----
    float b2v[4], w3v[4];
    #pragma unroll
    for (int bf = 0; bf < 4; ++bf) {
        int n = w * 64 + 16 * bf + (l & 15);
        b2v[bf] = b2[n];
        w3v[bf] = W3[n];
    }
    f32x2 ps[4][2];
    #pragma unroll
    for (int a = 0; a < 4; ++a) {
        ps[a][0] = f32x2{0.f, 0.f};
        ps[a][1] = f32x2{0.f, 0.f};
    }

    #pragma unroll
    for (int bf = 0; bf < 4; ++bf) {
        const f32x2 b2p = {b2v[bf], b2v[bf]};
        const f32x2 w3p = {w3v[bf], w3v[bf]};
        #pragma unroll
        for (int a = 0; a < 4; ++a) {
            f32x2 xlo = f32x2{acc[a][bf][0], acc[a][bf][1]} + b2p;
            f32x2 xhi = f32x2{acc[a][bf][2], acc[a][bf][3]} + b2p;
            ps[a][0] = __builtin_elementwise_fma(gelu_pk(xlo), w3p, ps[a][0]);
            ps[a][1] = __builtin_elementwise_fma(gelu_pk(xhi), w3p, ps[a][1]);
        }
    }

    float psum[4][4];
    #pragma unroll
    for (int a = 0; a < 4; ++a) {
        psum[a][0] = ps[a][0].x; psum[a][1] = ps[a][0].y;
        psum[a][2] = ps[a][1].x; psum[a][3] = ps[a][1].y;
    }

    #pragma unroll
    for (int a = 0; a < 4; ++a)
        #pragma unroll
        for (int r = 0; r < 4; ++r) {
            float v = psum[a][r];
            v += __shfl_xor(v, 1);
            v += __shfl_xor(v, 2);
            v += __shfl_xor(v, 4);
            v += __shfl_xor(v, 8);
            psum[a][r] = v;
        }

    if ((l & 15) == 0) {
        int gb = (l >> 4) * 4;
        #pragma unroll
        for (int a = 0; a < 4; ++a)
            #pragma unroll
            for (int r = 0; r < 4; ++r)
                lred[w][16 * a + gb + r] = psum[a][r];
    }
    __syncthreads();
    if (t < 64) {
        float s = b3[0];
        #pragma unroll
        for (int ww = 0; ww < 8; ++ww) s += lred[ww][t];
        out[r0 + t] = s;
    }
}

extern "C" void kernel_launch(void* const* d_in, const int* in_sizes, int n_in,
                              void* d_out, int out_size, void* d_ws, size_t ws_size,
                              hipStream_t stream) {
    (void)in_sizes; (void)n_in; (void)out_size; (void)ws_size;
    const float* g_q = (const float*)d_in[0];
    const float* Phi = (const float*)d_in[1];
    const float* W1  = (const float*)d_in[2];
    const float* b1  = (const float*)d_in[3];
    const float* W2  = (const float*)d_in[4];
    const float* b2  = (const float*)d_in[5];
    const float* W3  = (const float*)d_in[6];
    const float* b3  = (const float*)d_in[7];
    float* out = (float*)d_out;

    char* ws = (char*)d_ws;
    float*          hzb = (float*)ws;                            // 256 KB
    unsigned short* hpb = (unsigned short*)(ws + 262144);        // 1 MB
    unsigned short* W2F = (unsigned short*)(ws + 1310720);       // 512 KB

    hipLaunchKernelGGL(prep_kernel, dim3(136), dim3(512), 0, stream,
                       g_q, Phi, W1, b1, W2, hzb, hpb, W2F);
    hipLaunchKernelGGL(fused_kernel, dim3(2048), dim3(512), 0, stream,
                       hzb, hpb, W2F, b2, W3, b3, out);
}

// Round 15
// 122.822 us; speedup vs baseline: 1.3265x; 1.3265x over previous
//
#include <hip/hip_runtime.h>
#include <hip/hip_bf16.h>

// Sizes (fixed): B=128, M=1024, D_Z=1024, D_PHI=512, H1=512, H2=512
// ws: hzb f32[128*512] @0 (256K) | hpb bf16[1024*512] @256K (1M) |
//     W2F bf16[512*512] @1.25M (512K) | W1F bf16[1536*512] @1.75M (1.5M)
//
// Frag layout (W1F, W2F): B-frag for (kc=k>>5, nf=n>>4) is 1024B contiguous:
//   idx = (kc*32 + nf)*512 + lane*8, lane=(n&15)+16*((k>>3)&3), holds W[k..k+8][n].
//
// RULES LEARNED:
//  r7:  keep VGPR+AGPR <= 128/thread (4 waves/SIMD).
//  r8/r9: gelu is VALU-issue-heavy -> packed fp32.
//  r10: NO control-flow duplication around acc. Straight-line bodies only.
//  r11/r12: fused-body schedule restructures all lose; r9 body is the floor.
//  r13/r14: prep restructures (A-frag pass, W1-gather mega-kernel) all lose;
//           r9's wcast+l1 trio (~18us) is the best prep path.
//  r15: halve W2F L2 traffic (1.07GB->0.5GB) via 128-row blocks with the
//       SAME per-wave body (16 waves, wave 64x64, 4 waves/SIMD preserved).

typedef __bf16 bf16x8 __attribute__((ext_vector_type(8)));
typedef float  f32x4  __attribute__((ext_vector_type(4)));
typedef float  f32x2  __attribute__((ext_vector_type(2)));

__device__ __forceinline__ f32x2 gelu_pk(f32x2 x) {
    f32x2 t = x * x;
    f32x2 p = __builtin_elementwise_fma(t, f32x2{0.1029436f, 0.1029436f},
                                        f32x2{2.3022082f, 2.3022082f});
    f32x2 a = p * x;
    f32x2 e;
    e.x = __builtin_amdgcn_exp2f(a.x);
    e.y = __builtin_amdgcn_exp2f(a.y);
    f32x2 d = e + f32x2{1.f, 1.f};
    f32x2 r;
    r.x = __builtin_amdgcn_rcpf(d.x);
    r.y = __builtin_amdgcn_rcpf(d.y);
    return __builtin_elementwise_fma(-x, r, x);   // x - x*r
}

__device__ __forceinline__ unsigned int pack_bf16x2(float a, float b) {
    __hip_bfloat162 h = __float22bfloat162_rn(make_float2(a, b));
    return *reinterpret_cast<unsigned int*>(&h);
}
__device__ __forceinline__ float bf_lo(unsigned int u) {
    return __builtin_bit_cast(float, u << 16);
}
__device__ __forceinline__ float bf_hi(unsigned int u) {
    return __builtin_bit_cast(float, u & 0xffff0000u);
}

// ---------------- P1: wcast — W2 (64 blocks) + W1 (192 blocks) -> frag bf16 ----------------
__global__ __launch_bounds__(256) void wcast_kernel(
    const float* __restrict__ W1, const float* __restrict__ W2,
    unsigned short* __restrict__ W1F, unsigned short* __restrict__ W2F)
{
    __shared__ float tr[64 * 68];   // 17 KB
    const int t = threadIdx.x;
    const int id = blockIdx.x;

    const float* src;
    unsigned short* dst;
    int kt, nt;
    if (id < 64) { src = W2; dst = W2F; kt = id >> 3; nt = id & 7; }
    else         { src = W1; dst = W1F; kt = (id - 64) >> 3; nt = (id - 64) & 7; }
    const int k0 = kt * 64, n0 = nt * 64;

    {
        int r = t >> 2, c16 = (t & 3) * 16;
        #pragma unroll
        for (int q = 0; q < 4; ++q)
            *(float4*)&tr[r * 68 + c16 + q * 4] =
                *(const float4*)&src[(k0 + r) * 512 + n0 + c16 + q * 4];
    }
    __syncthreads();
    const int nl = t >> 2, kc16 = (t & 3) * 16;
    unsigned int pk[8];
    #pragma unroll
    for (int i = 0; i < 8; ++i) {
        float f0 = tr[(kc16 + 2 * i    ) * 68 + nl];
        float f1 = tr[(kc16 + 2 * i + 1) * 68 + nl];
        pk[i] = pack_bf16x2(f0, f1);
    }
    const int n  = n0 + nl;
    const int nf = n >> 4;
    #pragma unroll
    for (int h = 0; h < 2; ++h) {
        int kbase = k0 + kc16 + h * 8;
        int kc = kbase >> 5;
        int k8 = (kbase >> 3) & 3;
        int lane = (n & 15) + 16 * k8;
        uint4 v = h ? make_uint4(pk[4], pk[5], pk[6], pk[7])
                    : make_uint4(pk[0], pk[1], pk[2], pk[3]);
        *(uint4*)&dst[(unsigned)((kc * 32 + nf) * 512 + lane * 8)] = v;
    }
}

// ---------------- P2: l1 — MFMA GEMM for layer 1 (r9 verbatim) ----------------
__global__ __launch_bounds__(512) void l1_kernel(
    const float* __restrict__ g_q, const float* __restrict__ Phi,
    const unsigned short* __restrict__ W1F, const float* __restrict__ b1,
    float* __restrict__ hzb, unsigned short* __restrict__ hpb)
{
    __shared__ __align__(16) unsigned short lA[64 * 64];   // 8 KB

    const int t = threadIdx.x;
    const int w = t >> 6;
    const int l = t & 63;
    const int bi = blockIdx.x;
    const bool is_hz = bi < 2;
    const int r0 = is_hz ? bi * 64 : (bi - 2) * 64;
    const int ld = is_hz ? 1024 : 512;
    const int nkt = is_hz ? 16 : 8;
    const int kcb = is_hz ? 0 : 32;
    const float* src = is_hz ? g_q : Phi;

    f32x4 acc[4][4];
    #pragma unroll
    for (int a = 0; a < 4; ++a)
        #pragma unroll
        for (int bf = 0; bf < 4; ++bf)
            acc[a][bf] = f32x4{0.f, 0.f, 0.f, 0.f};

    const int arow = t >> 3;
    const int ac   = t & 7;
    const float* srow = src + (unsigned)(r0 + arow) * ld;
    const unsigned int awoff = (unsigned)(arow * 128 + ((ac ^ (arow & 7)) << 4));

    #pragma unroll 1
    for (int kt = 0; kt < nkt; ++kt) {
        uint4 breg[2][4];
        #pragma unroll
        for (int kk = 0; kk < 2; ++kk)
            #pragma unroll
            for (int bf = 0; bf < 4; ++bf)
                breg[kk][bf] = *(const uint4*)
                    &W1F[(unsigned)(((kcb + kt * 2 + kk) * 32 + w * 4 + bf) * 512 + l * 8)];

        {
            float4 p0 = *(const float4*)&srow[kt * 64 + ac * 8];
            float4 p1 = *(const float4*)&srow[kt * 64 + ac * 8 + 4];
            uint4 pk;
            pk.x = pack_bf16x2(p0.x, p0.y);
            pk.y = pack_bf16x2(p0.z, p0.w);
            pk.z = pack_bf16x2(p1.x, p1.y);
            pk.w = pack_bf16x2(p1.z, p1.w);
            *(uint4*)((char*)lA + awoff) = pk;
        }
        __syncthreads();

        #pragma unroll
        for (int kk = 0; kk < 2; ++kk) {
            const int cch = kk * 4 + (l >> 4);
            bf16x8 af[4];
            #pragma unroll
            for (int a = 0; a < 4; ++a) {
                int row = 16 * a + (l & 15);
                unsigned off = (unsigned)(row * 128 + ((cch ^ (row & 7)) << 4));
                af[a] = __builtin_bit_cast(bf16x8, *(const uint4*)((const char*)lA + off));
            }
            #pragma unroll
            for (int bf = 0; bf < 4; ++bf) {
                bf16x8 bfr = __builtin_bit_cast(bf16x8, breg[kk][bf]);
                #pragma unroll
                for (int a = 0; a < 4; ++a)
                    acc[a][bf] = __builtin_amdgcn_mfma_f32_16x16x32_bf16(
                        af[a], bfr, acc[a][bf], 0, 0, 0);
            }
        }
        __syncthreads();
    }

    const int cl = l & 15, rq = (l >> 4) * 4;
    #pragma unroll
    for (int bf = 0; bf < 4; ++bf) {
        int n = w * 64 + 16 * bf + cl;
        if (is_hz) {
            float bb = b1[n];
            #pragma unroll
            for (int a = 0; a < 4; ++a)
                #pragma unroll
                for (int r = 0; r < 4; ++r)
                    hzb[(unsigned)(r0 + 16 * a + rq + r) * 512 + n] = acc[a][bf][r] + bb;
        } else {
            #pragma unroll
            for (int a = 0; a < 4; ++a)
                #pragma unroll
                for (int r = 0; r < 4; ++r) {
                    __hip_bfloat16 v = __float2bfloat16(acc[a][bf][r]);
                    hpb[(unsigned)(r0 + 16 * a + rq + r) * 512 + n] =
                        *reinterpret_cast<unsigned short*>(&v);
                }
        }
    }
}

// ---------------- fused: gelu1 -> bf16 GEMM (x W2) -> gelu2 -> dot W3 ----------------
// r9 per-wave body, 128-row blocks: 1024 thr = 16 waves (2 rowgrp x 8 colgrp),
// wave tile 64x64 (acc 4x4). Halves W2F L2 traffic vs 64-row blocks.
// lA 2x16KB, hstage 2x16KB, one barrier per kt, packed gelu.
__global__ __launch_bounds__(1024) void fused_kernel(
    const float* __restrict__ hzb, const unsigned short* __restrict__ hpb,
    const unsigned short* __restrict__ W2F,
    const float* __restrict__ b2, const float* __restrict__ W3,
    const float* __restrict__ b3, float* __restrict__ out)
{
    __shared__ __align__(16) unsigned short lA[2 * 128 * 64];     // 32 KB
    __shared__ __align__(16) unsigned short hstage[2 * 128 * 64]; // 32 KB
    __shared__ __align__(16) float lhz[512];
    __shared__ float lred[16][64];

    const int t = threadIdx.x;
    const int w = __builtin_amdgcn_readfirstlane(t >> 6);  // wave 0..15
    const int l = t & 63;
    const int rg = w >> 3;          // row group (64 rows)
    const int cg = w & 7;           // col group (64 cols)
    const int r0 = blockIdx.x * 128;
    const int b  = r0 >> 10;
    const int m0 = r0 & 1023;

    f32x4 acc[4][4];
    #pragma unroll
    for (int a = 0; a < 4; ++a)
        #pragma unroll
        for (int bf = 0; bf < 4; ++bf)
            acc[a][bf] = f32x4{0.f, 0.f, 0.f, 0.f};

    const int arow = t >> 3;        // 0..127
    const int ac   = t & 7;
    const unsigned short* hprow = hpb + (unsigned)(m0 + arow) * 512;
    const float4* lhz4 = (const float4*)lhz;
    const unsigned int awoff = (unsigned)(arow * 128 + ((ac ^ (arow & 7)) << 4));
    const unsigned int hoff  = (unsigned)(t * 16);

    auto HPSTAGE = [&](int kt, int buf) {
        __builtin_amdgcn_global_load_lds(
            (const __attribute__((address_space(1))) void*)(hprow + kt * 64 + ac * 8),
            (__attribute__((address_space(3))) void*)((char*)hstage + buf * 16384 + hoff),
            16, 0, 0);
    };

    auto AGEN = [&](int kt, int abuf) {
        uint4 hv = *(const uint4*)((const char*)hstage + (kt & 1) * 16384 + hoff);
        const int kb = kt * 64 + ac * 8;
        float4 z0 = lhz4[kb >> 2];
        float4 z1 = lhz4[(kb >> 2) + 1];
        f32x2 g0 = gelu_pk(f32x2{bf_lo(hv.x), bf_hi(hv.x)} + f32x2{z0.x, z0.y});
        f32x2 g1 = gelu_pk(f32x2{bf_lo(hv.y), bf_hi(hv.y)} + f32x2{z0.z, z0.w});
        f32x2 g2 = gelu_pk(f32x2{bf_lo(hv.z), bf_hi(hv.z)} + f32x2{z1.x, z1.y});
        f32x2 g3 = gelu_pk(f32x2{bf_lo(hv.w), bf_hi(hv.w)} + f32x2{z1.z, z1.w});
        uint4 pk;
        pk.x = pack_bf16x2(g0.x, g0.y);
        pk.y = pack_bf16x2(g1.x, g1.y);
        pk.z = pack_bf16x2(g2.x, g2.y);
        pk.w = pack_bf16x2(g3.x, g3.y);
        *(uint4*)((char*)lA + (unsigned)(abuf * 16384) + awoff) = pk;
    };

    // ---- prologue ----
    HPSTAGE(0, 0);
    HPSTAGE(1, 1);
    if (t < 512) lhz[t] = hzb[b * 512 + t];
    __syncthreads();            // vmcnt drain: hstage0/1 + lhz ready
    AGEN(0, 0);
    __syncthreads();            // lA[0] ready

    // ---- main loop: one barrier per kt (r9 schedule) ----
    #pragma unroll 2
    for (int kt = 0; kt < 8; ++kt) {
        if (kt < 6) HPSTAGE(kt + 2, kt & 1);

        uint4 breg[2][4];
        #pragma unroll
        for (int kk = 0; kk < 2; ++kk)
            #pragma unroll
            for (int bf = 0; bf < 4; ++bf)
                breg[kk][bf] = *(const uint4*)
                    &W2F[(unsigned)(((kt * 2 + kk) * 32 + cg * 4 + bf) * 512 + l * 8)];

        if (kt < 7) AGEN(kt + 1, (kt + 1) & 1);

        const char* abase = (const char*)lA + (kt & 1) * 16384;
        #pragma unroll
        for (int kk = 0; kk < 2; ++kk) {
            const int cch = kk * 4 + (l >> 4);
            bf16x8 af[4];
            #pragma unroll
            for (int a = 0; a < 4; ++a) {
                int row = rg * 64 + 16 * a + (l & 15);
                unsigned off = (unsigned)(row * 128 + ((cch ^ (row & 7)) << 4));
                af[a] = __builtin_bit_cast(bf16x8, *(const uint4*)(abase + off));
            }
            #pragma unroll
            for (int bf = 0; bf < 4; ++bf) {
                bf16x8 bfr = __builtin_bit_cast(bf16x8, breg[kk][bf]);
                #pragma unroll
                for (int a = 0; a < 4; ++a)
                    acc[a][bf] = __builtin_amdgcn_mfma_f32_16x16x32_bf16(
                        af[a], bfr, acc[a][bf], 0, 0, 0);
            }
        }

        __syncthreads();
    }

    // ---- epilogue: +b2, gelu2 (packed), dot W3, reduce ----
    float b2v[4], w3v[4];
    #pragma unroll
    for (int bf = 0; bf < 4; ++bf) {
        int n = cg * 64 + 16 * bf + (l & 15);
        b2v[bf] = b2[n];
        w3v[bf] = W3[n];
    }
    f32x2 ps[4][2];
    #pragma unroll
    for (int a = 0; a < 4; ++a) {
        ps[a][0] = f32x2{0.f, 0.f};
        ps[a][1] = f32x2{0.f, 0.f};
    }

    #pragma unroll
    for (int bf = 0; bf < 4; ++bf) {
        const f32x2 b2p = {b2v[bf], b2v[bf]};
        const f32x2 w3p = {w3v[bf], w3v[bf]};
        #pragma unroll
        for (int a = 0; a < 4; ++a) {
            f32x2 xlo = f32x2{acc[a][bf][0], acc[a][bf][1]} + b2p;
            f32x2 xhi = f32x2{acc[a][bf][2], acc[a][bf][3]} + b2p;
            ps[a][0] = __builtin_elementwise_fma(gelu_pk(xlo), w3p, ps[a][0]);
            ps[a][1] = __builtin_elementwise_fma(gelu_pk(xhi), w3p, ps[a][1]);
        }
    }

    float psum[4][4];
    #pragma unroll
    for (int a = 0; a < 4; ++a) {
        psum[a][0] = ps[a][0].x; psum[a][1] = ps[a][0].y;
        psum[a][2] = ps[a][1].x; psum[a][3] = ps[a][1].y;
    }

    #pragma unroll
    for (int a = 0; a < 4; ++a)
        #pragma unroll
        for (int r = 0; r < 4; ++r) {
            float v = psum[a][r];
            v += __shfl_xor(v, 1);
            v += __shfl_xor(v, 2);
            v += __shfl_xor(v, 4);
            v += __shfl_xor(v, 8);
            psum[a][r] = v;
        }

    if ((l & 15) == 0) {
        int gb = (l >> 4) * 4;
        #pragma unroll
        for (int a = 0; a < 4; ++a)
            #pragma unroll
            for (int r = 0; r < 4; ++r)
                lred[w][16 * a + gb + r] = psum[a][r];
    }
    __syncthreads();
    if (t < 128) {
        const int rg2 = t >> 6, rr = t & 63;
        float s = b3[0];
        #pragma unroll
        for (int cw = 0; cw < 8; ++cw) s += lred[rg2 * 8 + cw][rr];
        out[r0 + t] = s;
    }
}

extern "C" void kernel_launch(void* const* d_in, const int* in_sizes, int n_in,
                              void* d_out, int out_size, void* d_ws, size_t ws_size,
                              hipStream_t stream) {
    (void)in_sizes; (void)n_in; (void)out_size; (void)ws_size;
    const float* g_q = (const float*)d_in[0];
    const float* Phi = (const float*)d_in[1];
    const float* W1  = (const float*)d_in[2];
    const float* b1  = (const float*)d_in[3];
    const float* W2  = (const float*)d_in[4];
    const float* b2  = (const float*)d_in[5];
    const float* W3  = (const float*)d_in[6];
    const float* b3  = (const float*)d_in[7];
    float* out = (float*)d_out;

    char* ws = (char*)d_ws;
    float*          hzb = (float*)ws;                                    // 256 KB
    unsigned short* hpb = (unsigned short*)(ws + 262144);                // 1 MB
    unsigned short* W2F = (unsigned short*)(ws + 1310720);               // 512 KB
    unsigned short* W1F = (unsigned short*)(ws + 1835008);               // 1.5 MB

    hipLaunchKernelGGL(wcast_kernel, dim3(256), dim3(256), 0, stream,
                       W1, W2, W1F, W2F);
    hipLaunchKernelGGL(l1_kernel, dim3(18), dim3(512), 0, stream,
                       g_q, Phi, W1F, b1, hzb, hpb);
    hipLaunchKernelGGL(fused_kernel, dim3(1024), dim3(1024), 0, stream,
                       hzb, hpb, W2F, b2, W3, b3, out);
}

// Round 16
// 113.544 us; speedup vs baseline: 1.4349x; 1.0817x over previous
//
#include <hip/hip_runtime.h>
#include <hip/hip_bf16.h>

// Sizes (fixed): B=128, M=1024, D_Z=1024, D_PHI=512, H1=512, H2=512
// ws: hzb f32[128*512] @0 (256K) | hpb bf16[1024*512] @256K (1M) |
//     W2F bf16[512*512] @1.25M (512K) | W1F bf16[1536*512] @1.75M (1.5M)
//
// Frag layout (W1F, W2F): B-frag for (kc=k>>5, nf=n>>4) is 1024B contiguous:
//   idx = (kc*32 + nf)*512 + lane*8, lane=(n&15)+16*((k>>3)&3), holds W[k..k+8][n].
//
// RULES LEARNED:
//  r7:  keep VGPR+AGPR <= 128/thread (4 waves/SIMD).
//  r8/r9: gelu is VALU-issue-heavy -> packed fp32.
//  r10: NO control-flow duplication around acc. Straight-line bodies only.
//  r11/r12/r15: fused-body restructures (rings, parity, interleave, wide
//       blocks) ALL lose; r9 fused (97.4us, 82% aggregate issue util) is
//       the floor of this structure. DO NOT TOUCH.
//  r13/r14: prep rewrites lose; r16 = consolidation only: W2F-cast blocks
//       merged into l1 launch (no dependency), l1 col-split 2x (36 blocks).

typedef __bf16 bf16x8 __attribute__((ext_vector_type(8)));
typedef float  f32x4  __attribute__((ext_vector_type(4)));
typedef float  f32x2  __attribute__((ext_vector_type(2)));

__device__ __forceinline__ f32x2 gelu_pk(f32x2 x) {
    f32x2 t = x * x;
    f32x2 p = __builtin_elementwise_fma(t, f32x2{0.1029436f, 0.1029436f},
                                        f32x2{2.3022082f, 2.3022082f});
    f32x2 a = p * x;
    f32x2 e;
    e.x = __builtin_amdgcn_exp2f(a.x);
    e.y = __builtin_amdgcn_exp2f(a.y);
    f32x2 d = e + f32x2{1.f, 1.f};
    f32x2 r;
    r.x = __builtin_amdgcn_rcpf(d.x);
    r.y = __builtin_amdgcn_rcpf(d.y);
    return __builtin_elementwise_fma(-x, r, x);   // x - x*r
}

__device__ __forceinline__ unsigned int pack_bf16x2(float a, float b) {
    __hip_bfloat162 h = __float22bfloat162_rn(make_float2(a, b));
    return *reinterpret_cast<unsigned int*>(&h);
}
__device__ __forceinline__ float bf_lo(unsigned int u) {
    return __builtin_bit_cast(float, u << 16);
}
__device__ __forceinline__ float bf_hi(unsigned int u) {
    return __builtin_bit_cast(float, u & 0xffff0000u);
}

// ---------------- P1: wcast — W1 only (192 blocks) -> W1F frag bf16 ----------------
__global__ __launch_bounds__(256) void wcast_kernel(
    const float* __restrict__ W1, unsigned short* __restrict__ W1F)
{
    __shared__ float tr[64 * 68];   // 17 KB
    const int t = threadIdx.x;
    const int id = blockIdx.x;
    const int kt = id >> 3, nt = id & 7;
    const int k0 = kt * 64, n0 = nt * 64;

    {
        int r = t >> 2, c16 = (t & 3) * 16;
        #pragma unroll
        for (int q = 0; q < 4; ++q)
            *(float4*)&tr[r * 68 + c16 + q * 4] =
                *(const float4*)&W1[(k0 + r) * 512 + n0 + c16 + q * 4];
    }
    __syncthreads();
    const int nl = t >> 2, kc16 = (t & 3) * 16;
    unsigned int pk[8];
    #pragma unroll
    for (int i = 0; i < 8; ++i) {
        float f0 = tr[(kc16 + 2 * i    ) * 68 + nl];
        float f1 = tr[(kc16 + 2 * i + 1) * 68 + nl];
        pk[i] = pack_bf16x2(f0, f1);
    }
    const int n  = n0 + nl;
    const int nf = n >> 4;
    #pragma unroll
    for (int h = 0; h < 2; ++h) {
        int kbase = k0 + kc16 + h * 8;
        int kc = kbase >> 5;
        int k8 = (kbase >> 3) & 3;
        int lane = (n & 15) + 16 * k8;
        uint4 v = h ? make_uint4(pk[4], pk[5], pk[6], pk[7])
                    : make_uint4(pk[0], pk[1], pk[2], pk[3]);
        *(uint4*)&W1F[(unsigned)((kc * 32 + nf) * 512 + lane * 8)] = v;
    }
}

// ---------------- P2: l1w2 — W2F cast (64 blocks) + l1 GEMM (36 blocks) ----------------
// grid 100 x 256:
//   [0,64):   W2F transpose-cast 64x64 tiles (same code as wcast, src=W2)
//   [64,68):  hz blocks: 64 rows x 256 cols, K=1024 (2 row-tiles x 2 col-tiles)
//   [68,100): hp blocks: 64 rows x 256 cols, K=512  (16 row-tiles x 2 col-tiles)
// l1 blocks: 4 waves, wave tile 64x64 (acc 4x4) — per-wave body identical to
// the proven r9 l1; A-tile staged by 256 threads (2 chunks each).
__global__ __launch_bounds__(256) void l1w2_kernel(
    const float* __restrict__ g_q, const float* __restrict__ Phi,
    const float* __restrict__ W2,
    const unsigned short* __restrict__ W1F, const float* __restrict__ b1,
    float* __restrict__ hzb, unsigned short* __restrict__ hpb,
    unsigned short* __restrict__ W2F)
{
    __shared__ __align__(16) float trf[64 * 68];   // 17 KB; l1 aliases first 8 KB
    const int t = threadIdx.x;
    const int id = blockIdx.x;

    if (id < 64) {
        // ----- W2F: transpose-cast one 64x64 tile -----
        const int kt = id >> 3, nt = id & 7;
        const int k0 = kt * 64, n0 = nt * 64;
        {
            int r = t >> 2, c16 = (t & 3) * 16;
            #pragma unroll
            for (int q = 0; q < 4; ++q)
                *(float4*)&trf[r * 68 + c16 + q * 4] =
                    *(const float4*)&W2[(k0 + r) * 512 + n0 + c16 + q * 4];
        }
        __syncthreads();
        const int nl = t >> 2, kc16 = (t & 3) * 16;
        unsigned int pk[8];
        #pragma unroll
        for (int i = 0; i < 8; ++i) {
            float f0 = trf[(kc16 + 2 * i    ) * 68 + nl];
            float f1 = trf[(kc16 + 2 * i + 1) * 68 + nl];
            pk[i] = pack_bf16x2(f0, f1);
        }
        const int n  = n0 + nl;
        const int nf = n >> 4;
        #pragma unroll
        for (int h = 0; h < 2; ++h) {
            int kbase = k0 + kc16 + h * 8;
            int kc = kbase >> 5;
            int k8 = (kbase >> 3) & 3;
            int lane = (n & 15) + 16 * k8;
            uint4 v = h ? make_uint4(pk[4], pk[5], pk[6], pk[7])
                        : make_uint4(pk[0], pk[1], pk[2], pk[3]);
            *(uint4*)&W2F[(unsigned)((kc * 32 + nf) * 512 + lane * 8)] = v;
        }
    } else {
        // ----- l1 GEMM: 64 rows x 256 cols, 4 waves -----
        unsigned short* lA = (unsigned short*)trf;   // 8 KB A-tile
        const int bi = id - 64;
        const bool is_hz = bi < 4;
        int rt, ct;
        if (is_hz) { rt = bi >> 1;        ct = bi & 1; }
        else       { rt = (bi - 4) >> 1;  ct = (bi - 4) & 1; }
        const int r0 = rt * 64, c0 = ct * 256;
        const int ld = is_hz ? 1024 : 512;
        const int nkt = is_hz ? 16 : 8;
        const int kcb = is_hz ? 0 : 32;
        const float* src = is_hz ? g_q : Phi;

        const int w = t >> 6;       // 0..3
        const int l = t & 63;

        f32x4 acc[4][4];
        #pragma unroll
        for (int a = 0; a < 4; ++a)
            #pragma unroll
            for (int bf = 0; bf < 4; ++bf)
                acc[a][bf] = f32x4{0.f, 0.f, 0.f, 0.f};

        #pragma unroll 1
        for (int kt = 0; kt < nkt; ++kt) {
            uint4 breg[2][4];
            #pragma unroll
            for (int kk = 0; kk < 2; ++kk)
                #pragma unroll
                for (int bf = 0; bf < 4; ++bf)
                    breg[kk][bf] = *(const uint4*)
                        &W1F[(unsigned)(((kcb + kt * 2 + kk) * 32 +
                                         ct * 16 + w * 4 + bf) * 512 + l * 8)];

            // stage A-tile 64x64: 512 chunks, 256 threads x 2
            #pragma unroll
            for (int h = 0; h < 2; ++h) {
                int ci = h * 256 + t;
                int arow = ci >> 3, ac = ci & 7;
                const float* srow = src + (unsigned)(r0 + arow) * ld;
                float4 p0 = *(const float4*)&srow[kt * 64 + ac * 8];
                float4 p1 = *(const float4*)&srow[kt * 64 + ac * 8 + 4];
                uint4 pk;
                pk.x = pack_bf16x2(p0.x, p0.y);
                pk.y = pack_bf16x2(p0.z, p0.w);
                pk.z = pack_bf16x2(p1.x, p1.y);
                pk.w = pack_bf16x2(p1.z, p1.w);
                *(uint4*)((char*)lA +
                          (unsigned)(arow * 128 + ((ac ^ (arow & 7)) << 4))) = pk;
            }
            __syncthreads();

            #pragma unroll
            for (int kk = 0; kk < 2; ++kk) {
                const int cch = kk * 4 + (l >> 4);
                bf16x8 af[4];
                #pragma unroll
                for (int a = 0; a < 4; ++a) {
                    int row = 16 * a + (l & 15);
                    unsigned off = (unsigned)(row * 128 + ((cch ^ (row & 7)) << 4));
                    af[a] = __builtin_bit_cast(bf16x8,
                                *(const uint4*)((const char*)lA + off));
                }
                #pragma unroll
                for (int bf = 0; bf < 4; ++bf) {
                    bf16x8 bfr = __builtin_bit_cast(bf16x8, breg[kk][bf]);
                    #pragma unroll
                    for (int a = 0; a < 4; ++a)
                        acc[a][bf] = __builtin_amdgcn_mfma_f32_16x16x32_bf16(
                            af[a], bfr, acc[a][bf], 0, 0, 0);
                }
            }
            __syncthreads();
        }

        const int cl = l & 15, rq = (l >> 4) * 4;
        #pragma unroll
        for (int bf = 0; bf < 4; ++bf) {
            int n = c0 + w * 64 + 16 * bf + cl;
            if (is_hz) {
                float bb = b1[n];
                #pragma unroll
                for (int a = 0; a < 4; ++a)
                    #pragma unroll
                    for (int r = 0; r < 4; ++r)
                        hzb[(unsigned)(r0 + 16 * a + rq + r) * 512 + n] =
                            acc[a][bf][r] + bb;
            } else {
                #pragma unroll
                for (int a = 0; a < 4; ++a)
                    #pragma unroll
                    for (int r = 0; r < 4; ++r) {
                        __hip_bfloat16 v = __float2bfloat16(acc[a][bf][r]);
                        hpb[(unsigned)(r0 + 16 * a + rq + r) * 512 + n] =
                            *reinterpret_cast<unsigned short*>(&v);
                    }
            }
        }
    }
}

// ---------------- fused: gelu1 -> bf16 GEMM (x W2) -> gelu2 -> dot W3 ----------------
// r9 VERBATIM: 64r x 512c, 8 waves, wave 64x64 (acc 4x4), one barrier/kt,
// B frags global->reg, hp via 2x8KB global_load_lds ring, packed gelu.
__global__ __launch_bounds__(512, 2) void fused_kernel(
    const float* __restrict__ hzb, const unsigned short* __restrict__ hpb,
    const unsigned short* __restrict__ W2F,
    const float* __restrict__ b2, const float* __restrict__ W3,
    const float* __restrict__ b3, float* __restrict__ out)
{
    __shared__ __align__(16) unsigned short lA[2 * 64 * 64];      // 16 KB
    __shared__ __align__(16) unsigned short hstage[2 * 64 * 64];  // 16 KB
    __shared__ __align__(16) float lhz[512];
    __shared__ float lred[8][64];

    const int t = threadIdx.x;
    const int w = __builtin_amdgcn_readfirstlane(t >> 6);  // wave id, SGPR
    const int l = t & 63;
    const int r0 = blockIdx.x * 64;
    const int b  = r0 >> 10;
    const int m0 = r0 & 1023;

    f32x4 acc[4][4];
    #pragma unroll
    for (int a = 0; a < 4; ++a)
        #pragma unroll
        for (int bf = 0; bf < 4; ++bf)
            acc[a][bf] = f32x4{0.f, 0.f, 0.f, 0.f};

    const int arow = t >> 3;
    const int ac   = t & 7;
    const unsigned short* hprow = hpb + (unsigned)(m0 + arow) * 512;
    const float4* lhz4 = (const float4*)lhz;
    const unsigned int awoff = (unsigned)(arow * 128 + ((ac ^ (arow & 7)) << 4));
    const unsigned int hoff  = (unsigned)(t * 16);

    auto HPSTAGE = [&](int kt, int buf) {
        __builtin_amdgcn_global_load_lds(
            (const __attribute__((address_space(1))) void*)(hprow + kt * 64 + ac * 8),
            (__attribute__((address_space(3))) void*)((char*)hstage + buf * 8192 + hoff),
            16, 0, 0);
    };

    auto AGEN = [&](int kt, int abuf) {
        uint4 hv = *(const uint4*)((const char*)hstage + (kt & 1) * 8192 + hoff);
        const int kb = kt * 64 + ac * 8;
        float4 z0 = lhz4[kb >> 2];
        float4 z1 = lhz4[(kb >> 2) + 1];
        f32x2 g0 = gelu_pk(f32x2{bf_lo(hv.x), bf_hi(hv.x)} + f32x2{z0.x, z0.y});
        f32x2 g1 = gelu_pk(f32x2{bf_lo(hv.y), bf_hi(hv.y)} + f32x2{z0.z, z0.w});
        f32x2 g2 = gelu_pk(f32x2{bf_lo(hv.z), bf_hi(hv.z)} + f32x2{z1.x, z1.y});
        f32x2 g3 = gelu_pk(f32x2{bf_lo(hv.w), bf_hi(hv.w)} + f32x2{z1.z, z1.w});
        uint4 pk;
        pk.x = pack_bf16x2(g0.x, g0.y);
        pk.y = pack_bf16x2(g1.x, g1.y);
        pk.z = pack_bf16x2(g2.x, g2.y);
        pk.w = pack_bf16x2(g3.x, g3.y);
        *(uint4*)((char*)lA + (unsigned)(abuf * 8192) + awoff) = pk;
    };

    // ---- prologue ----
    HPSTAGE(0, 0);
    HPSTAGE(1, 1);
    lhz[t] = hzb[b * 512 + t];
    __syncthreads();            // vmcnt drain: hstage0/1 + lhz ready
    AGEN(0, 0);
    __syncthreads();            // lA[0] ready

    // ---- main loop: one barrier per kt ----
    #pragma unroll 2
    for (int kt = 0; kt < 8; ++kt) {
        if (kt < 6) HPSTAGE(kt + 2, kt & 1);

        uint4 breg[2][4];
        #pragma unroll
        for (int kk = 0; kk < 2; ++kk)
            #pragma unroll
            for (int bf = 0; bf < 4; ++bf)
                breg[kk][bf] = *(const uint4*)
                    &W2F[(unsigned)(((kt * 2 + kk) * 32 + w * 4 + bf) * 512 + l * 8)];

        if (kt < 7) AGEN(kt + 1, (kt + 1) & 1);

        const char* abase = (const char*)lA + (kt & 1) * 8192;
        #pragma unroll
        for (int kk = 0; kk < 2; ++kk) {
            const int cch = kk * 4 + (l >> 4);
            bf16x8 af[4];
            #pragma unroll
            for (int a = 0; a < 4; ++a) {
                int row = 16 * a + (l & 15);
                unsigned off = (unsigned)(row * 128 + ((cch ^ (row & 7)) << 4));
                af[a] = __builtin_bit_cast(bf16x8, *(const uint4*)(abase + off));
            }
            #pragma unroll
            for (int bf = 0; bf < 4; ++bf) {
                bf16x8 bfr = __builtin_bit_cast(bf16x8, breg[kk][bf]);
                #pragma unroll
                for (int a = 0; a < 4; ++a)
                    acc[a][bf] = __builtin_amdgcn_mfma_f32_16x16x32_bf16(
                        af[a], bfr, acc[a][bf], 0, 0, 0);
            }
        }

        __syncthreads();
    }

    // ---- epilogue: +b2, gelu2 (packed), dot W3, reduce ----
    float b2v[4], w3v[4];
    #pragma unroll
    for (int bf = 0; bf < 4; ++bf) {
        int n = w * 64 + 16 * bf + (l & 15);
        b2v[bf] = b2[n];
        w3v[bf] = W3[n];
    }
    f32x2 ps[4][2];
    #pragma unroll
    for (int a = 0; a < 4; ++a) {
        ps[a][0] = f32x2{0.f, 0.f};
        ps[a][1] = f32x2{0.f, 0.f};
    }

    #pragma unroll
    for (int bf = 0; bf < 4; ++bf) {
        const f32x2 b2p = {b2v[bf], b2v[bf]};
        const f32x2 w3p = {w3v[bf], w3v[bf]};
        #pragma unroll
        for (int a = 0; a < 4; ++a) {
            f32x2 xlo = f32x2{acc[a][bf][0], acc[a][bf][1]} + b2p;
            f32x2 xhi = f32x2{acc[a][bf][2], acc[a][bf][3]} + b2p;
            ps[a][0] = __builtin_elementwise_fma(gelu_pk(xlo), w3p, ps[a][0]);
            ps[a][1] = __builtin_elementwise_fma(gelu_pk(xhi), w3p, ps[a][1]);
        }
    }

    float psum[4][4];
    #pragma unroll
    for (int a = 0; a < 4; ++a) {
        psum[a][0] = ps[a][0].x; psum[a][1] = ps[a][0].y;
        psum[a][2] = ps[a][1].x; psum[a][3] = ps[a][1].y;
    }

    #pragma unroll
    for (int a = 0; a < 4; ++a)
        #pragma unroll
        for (int r = 0; r < 4; ++r) {
            float v = psum[a][r];
            v += __shfl_xor(v, 1);
            v += __shfl_xor(v, 2);
            v += __shfl_xor(v, 4);
            v += __shfl_xor(v, 8);
            psum[a][r] = v;
        }

    if ((l & 15) == 0) {
        int gb = (l >> 4) * 4;
        #pragma unroll
        for (int a = 0; a < 4; ++a)
            #pragma unroll
            for (int r = 0; r < 4; ++r)
                lred[w][16 * a + gb + r] = psum[a][r];
    }
    __syncthreads();
    if (t < 64) {
        float s = b3[0];
        #pragma unroll
        for (int ww = 0; ww < 8; ++ww) s += lred[ww][t];
        out[r0 + t] = s;
    }
}

extern "C" void kernel_launch(void* const* d_in, const int* in_sizes, int n_in,
                              void* d_out, int out_size, void* d_ws, size_t ws_size,
                              hipStream_t stream) {
    (void)in_sizes; (void)n_in; (void)out_size; (void)ws_size;
    const float* g_q = (const float*)d_in[0];
    const float* Phi = (const float*)d_in[1];
    const float* W1  = (const float*)d_in[2];
    const float* b1  = (const float*)d_in[3];
    const float* W2  = (const float*)d_in[4];
    const float* b2  = (const float*)d_in[5];
    const float* W3  = (const float*)d_in[6];
    const float* b3  = (const float*)d_in[7];
    float* out = (float*)d_out;

    char* ws = (char*)d_ws;
    float*          hzb = (float*)ws;                                    // 256 KB
    unsigned short* hpb = (unsigned short*)(ws + 262144);                // 1 MB
    unsigned short* W2F = (unsigned short*)(ws + 1310720);               // 512 KB
    unsigned short* W1F = (unsigned short*)(ws + 1835008);               // 1.5 MB

    hipLaunchKernelGGL(wcast_kernel, dim3(192), dim3(256), 0, stream,
                       W1, W1F);
    hipLaunchKernelGGL(l1w2_kernel, dim3(100), dim3(256), 0, stream,
                       g_q, Phi, W2, W1F, b1, hzb, hpb, W2F);
    hipLaunchKernelGGL(fused_kernel, dim3(2048), dim3(512), 0, stream,
                       hzb, hpb, W2F, b2, W3, b3, out);
}

// Round 17
// 106.254 us; speedup vs baseline: 1.5333x; 1.0686x over previous
//
#include <hip/hip_runtime.h>
#include <hip/hip_bf16.h>

// Sizes (fixed): B=128, M=1024, D_Z=1024, D_PHI=512, H1=512, H2=512
// ws: hz_part f32[2][128*512] @0 (512K) | hpb bf16[1024*512] @512K (1M) |
//     W2F bf16[512*512] @1.5M (512K) | W1F bf16[1536*512] @2M (1.5M)
//
// Frag layout (W1F, W2F): B-frag for (kc=k>>5, nf=n>>4) is 1024B contiguous:
//   idx = (kc*32 + nf)*512 + lane*8, lane=(n&15)+16*((k>>3)&3), holds W[k..k+8][n].
//
// RULES LEARNED:
//  r7:  keep VGPR+AGPR <= 128/thread (4 waves/SIMD).
//  r8/r9: gelu is VALU-issue-heavy -> packed fp32.
//  r10: NO control-flow duplication around acc. Straight-line bodies only.
//  r11/r12/r15: fused-body restructures ALL lose; r9 fused (97.4us) is the
//       floor of this structure. DO NOT TOUCH (only prologue lhz line changed).
//  r13/r14: prep rewrites lose; consolidate only.
//  r17: hz K-split x2 (16-kt chain -> 8-kt), combine folded into fused
//       prologue (lhz = hz0+hz1+b1); l1w2 all-512-thread, 84 blocks.

typedef __bf16 bf16x8 __attribute__((ext_vector_type(8)));
typedef float  f32x4  __attribute__((ext_vector_type(4)));
typedef float  f32x2  __attribute__((ext_vector_type(2)));

__device__ __forceinline__ f32x2 gelu_pk(f32x2 x) {
    f32x2 t = x * x;
    f32x2 p = __builtin_elementwise_fma(t, f32x2{0.1029436f, 0.1029436f},
                                        f32x2{2.3022082f, 2.3022082f});
    f32x2 a = p * x;
    f32x2 e;
    e.x = __builtin_amdgcn_exp2f(a.x);
    e.y = __builtin_amdgcn_exp2f(a.y);
    f32x2 d = e + f32x2{1.f, 1.f};
    f32x2 r;
    r.x = __builtin_amdgcn_rcpf(d.x);
    r.y = __builtin_amdgcn_rcpf(d.y);
    return __builtin_elementwise_fma(-x, r, x);   // x - x*r
}

__device__ __forceinline__ unsigned int pack_bf16x2(float a, float b) {
    __hip_bfloat162 h = __float22bfloat162_rn(make_float2(a, b));
    return *reinterpret_cast<unsigned int*>(&h);
}
__device__ __forceinline__ float bf_lo(unsigned int u) {
    return __builtin_bit_cast(float, u << 16);
}
__device__ __forceinline__ float bf_hi(unsigned int u) {
    return __builtin_bit_cast(float, u & 0xffff0000u);
}

// ---------------- P1: wcast — W1 only (192 blocks x 256 thr) -> W1F ----------------
__global__ __launch_bounds__(256) void wcast_kernel(
    const float* __restrict__ W1, unsigned short* __restrict__ W1F)
{
    __shared__ float tr[64 * 68];   // 17 KB
    const int t = threadIdx.x;
    const int id = blockIdx.x;
    const int kt = id >> 3, nt = id & 7;
    const int k0 = kt * 64, n0 = nt * 64;

    {
        int r = t >> 2, c16 = (t & 3) * 16;
        #pragma unroll
        for (int q = 0; q < 4; ++q)
            *(float4*)&tr[r * 68 + c16 + q * 4] =
                *(const float4*)&W1[(k0 + r) * 512 + n0 + c16 + q * 4];
    }
    __syncthreads();
    const int nl = t >> 2, kc16 = (t & 3) * 16;
    unsigned int pk[8];
    #pragma unroll
    for (int i = 0; i < 8; ++i) {
        float f0 = tr[(kc16 + 2 * i    ) * 68 + nl];
        float f1 = tr[(kc16 + 2 * i + 1) * 68 + nl];
        pk[i] = pack_bf16x2(f0, f1);
    }
    const int n  = n0 + nl;
    const int nf = n >> 4;
    #pragma unroll
    for (int h = 0; h < 2; ++h) {
        int kbase = k0 + kc16 + h * 8;
        int kc = kbase >> 5;
        int k8 = (kbase >> 3) & 3;
        int lane = (n & 15) + 16 * k8;
        uint4 v = h ? make_uint4(pk[4], pk[5], pk[6], pk[7])
                    : make_uint4(pk[0], pk[1], pk[2], pk[3]);
        *(uint4*)&W1F[(unsigned)((kc * 32 + nf) * 512 + lane * 8)] = v;
    }
}

// ---------------- P2: l1w2 — W2F cast (64) + hz-partials (4) + hp (16), 512 thr ----------------
// grid 84 x 512:
//   [0,64):  W2F transpose-cast 64x64 tiles (512-thr variant, proven r14)
//   [64,68): hz partial: (rt, ks) = (bi>>1, bi&1); 64r x 512c, K=512 half;
//            writes hz_part[ks] WITHOUT b1 (combine folded into fused)
//   [68,84): hp: 64r x 512c, K=512 -> bf16 hpb   (r9 l1 body verbatim)
__global__ __launch_bounds__(512) void l1w2_kernel(
    const float* __restrict__ g_q, const float* __restrict__ Phi,
    const float* __restrict__ W2,
    const unsigned short* __restrict__ W1F,
    float* __restrict__ hz_part, unsigned short* __restrict__ hpb,
    unsigned short* __restrict__ W2F)
{
    __shared__ __align__(16) float trf[64 * 68];   // 17 KB; l1 aliases first 8 KB
    const int t = threadIdx.x;
    const int id = blockIdx.x;

    if (id < 64) {
        // ----- W2F: transpose-cast one 64x64 tile (512 threads) -----
        const int kt = id >> 3, nt = id & 7;
        const int k0 = kt * 64, n0 = nt * 64;
        {
            int row = t >> 3, col = (t & 7) * 8;
            *(float4*)&trf[row * 68 + col] =
                *(const float4*)&W2[(k0 + row) * 512 + n0 + col];
            *(float4*)&trf[row * 68 + col + 4] =
                *(const float4*)&W2[(k0 + row) * 512 + n0 + col + 4];
        }
        __syncthreads();
        const int nl = t >> 3, kc16 = (t & 7) * 8;
        unsigned int pk[4];
        #pragma unroll
        for (int i = 0; i < 4; ++i) {
            float f0 = trf[(kc16 + 2 * i    ) * 68 + nl];
            float f1 = trf[(kc16 + 2 * i + 1) * 68 + nl];
            pk[i] = pack_bf16x2(f0, f1);
        }
        const int n   = n0 + nl;
        const int nf  = n >> 4;
        const int kbase = k0 + kc16;
        const int kc  = kbase >> 5;
        const int k8  = (kbase >> 3) & 3;
        const int lane = (n & 15) + 16 * k8;
        *(uint4*)&W2F[(unsigned)((kc * 32 + nf) * 512 + lane * 8)] =
            make_uint4(pk[0], pk[1], pk[2], pk[3]);
    } else {
        // ----- l1 GEMM (r9 body): 64r x 512c, 8 waves, 8 kt -----
        unsigned short* lA = (unsigned short*)trf;   // 8 KB A-tile
        const int bi = id - 64;
        const bool is_hz = bi < 4;
        const int rt = is_hz ? (bi >> 1) : (bi - 4);
        const int ks = is_hz ? (bi & 1) : 0;
        const int r0 = rt * 64;
        const int ld = is_hz ? 1024 : 512;
        const int kcb = is_hz ? ks * 16 : 32;
        const int ksoff = is_hz ? ks * 512 : 0;
        const float* src = is_hz ? g_q : Phi;

        const int w = t >> 6;
        const int l = t & 63;

        f32x4 acc[4][4];
        #pragma unroll
        for (int a = 0; a < 4; ++a)
            #pragma unroll
            for (int bf = 0; bf < 4; ++bf)
                acc[a][bf] = f32x4{0.f, 0.f, 0.f, 0.f};

        const int arow = t >> 3;
        const int ac   = t & 7;
        const float* srow = src + (unsigned)(r0 + arow) * ld + ksoff;
        const unsigned int awoff = (unsigned)(arow * 128 + ((ac ^ (arow & 7)) << 4));

        #pragma unroll 1
        for (int kt = 0; kt < 8; ++kt) {
            uint4 breg[2][4];
            #pragma unroll
            for (int kk = 0; kk < 2; ++kk)
                #pragma unroll
                for (int bf = 0; bf < 4; ++bf)
                    breg[kk][bf] = *(const uint4*)
                        &W1F[(unsigned)(((kcb + kt * 2 + kk) * 32 + w * 4 + bf) * 512 + l * 8)];

            {
                float4 p0 = *(const float4*)&srow[kt * 64 + ac * 8];
                float4 p1 = *(const float4*)&srow[kt * 64 + ac * 8 + 4];
                uint4 pk;
                pk.x = pack_bf16x2(p0.x, p0.y);
                pk.y = pack_bf16x2(p0.z, p0.w);
                pk.z = pack_bf16x2(p1.x, p1.y);
                pk.w = pack_bf16x2(p1.z, p1.w);
                *(uint4*)((char*)lA + awoff) = pk;
            }
            __syncthreads();

            #pragma unroll
            for (int kk = 0; kk < 2; ++kk) {
                const int cch = kk * 4 + (l >> 4);
                bf16x8 af[4];
                #pragma unroll
                for (int a = 0; a < 4; ++a) {
                    int row = 16 * a + (l & 15);
                    unsigned off = (unsigned)(row * 128 + ((cch ^ (row & 7)) << 4));
                    af[a] = __builtin_bit_cast(bf16x8,
                                *(const uint4*)((const char*)lA + off));
                }
                #pragma unroll
                for (int bf = 0; bf < 4; ++bf) {
                    bf16x8 bfr = __builtin_bit_cast(bf16x8, breg[kk][bf]);
                    #pragma unroll
                    for (int a = 0; a < 4; ++a)
                        acc[a][bf] = __builtin_amdgcn_mfma_f32_16x16x32_bf16(
                            af[a], bfr, acc[a][bf], 0, 0, 0);
                }
            }
            __syncthreads();
        }

        const int cl = l & 15, rq = (l >> 4) * 4;
        #pragma unroll
        for (int bf = 0; bf < 4; ++bf) {
            int n = w * 64 + 16 * bf + cl;
            if (is_hz) {
                float* dst = hz_part + ks * 65536;
                #pragma unroll
                for (int a = 0; a < 4; ++a)
                    #pragma unroll
                    for (int r = 0; r < 4; ++r)
                        dst[(unsigned)(r0 + 16 * a + rq + r) * 512 + n] = acc[a][bf][r];
            } else {
                #pragma unroll
                for (int a = 0; a < 4; ++a)
                    #pragma unroll
                    for (int r = 0; r < 4; ++r) {
                        __hip_bfloat16 v = __float2bfloat16(acc[a][bf][r]);
                        hpb[(unsigned)(r0 + 16 * a + rq + r) * 512 + n] =
                            *reinterpret_cast<unsigned short*>(&v);
                    }
            }
        }
    }
}

// ---------------- fused: gelu1 -> bf16 GEMM (x W2) -> gelu2 -> dot W3 ----------------
// r9 VERBATIM except prologue: lhz[t] = hz_part0 + hz_part1 + b1[t].
__global__ __launch_bounds__(512, 2) void fused_kernel(
    const float* __restrict__ hz_part, const float* __restrict__ b1,
    const unsigned short* __restrict__ hpb,
    const unsigned short* __restrict__ W2F,
    const float* __restrict__ b2, const float* __restrict__ W3,
    const float* __restrict__ b3, float* __restrict__ out)
{
    __shared__ __align__(16) unsigned short lA[2 * 64 * 64];      // 16 KB
    __shared__ __align__(16) unsigned short hstage[2 * 64 * 64];  // 16 KB
    __shared__ __align__(16) float lhz[512];
    __shared__ float lred[8][64];

    const int t = threadIdx.x;
    const int w = __builtin_amdgcn_readfirstlane(t >> 6);  // wave id, SGPR
    const int l = t & 63;
    const int r0 = blockIdx.x * 64;
    const int b  = r0 >> 10;
    const int m0 = r0 & 1023;

    f32x4 acc[4][4];
    #pragma unroll
    for (int a = 0; a < 4; ++a)
        #pragma unroll
        for (int bf = 0; bf < 4; ++bf)
            acc[a][bf] = f32x4{0.f, 0.f, 0.f, 0.f};

    const int arow = t >> 3;
    const int ac   = t & 7;
    const unsigned short* hprow = hpb + (unsigned)(m0 + arow) * 512;
    const float4* lhz4 = (const float4*)lhz;
    const unsigned int awoff = (unsigned)(arow * 128 + ((ac ^ (arow & 7)) << 4));
    const unsigned int hoff  = (unsigned)(t * 16);

    auto HPSTAGE = [&](int kt, int buf) {
        __builtin_amdgcn_global_load_lds(
            (const __attribute__((address_space(1))) void*)(hprow + kt * 64 + ac * 8),
            (__attribute__((address_space(3))) void*)((char*)hstage + buf * 8192 + hoff),
            16, 0, 0);
    };

    auto AGEN = [&](int kt, int abuf) {
        uint4 hv = *(const uint4*)((const char*)hstage + (kt & 1) * 8192 + hoff);
        const int kb = kt * 64 + ac * 8;
        float4 z0 = lhz4[kb >> 2];
        float4 z1 = lhz4[(kb >> 2) + 1];
        f32x2 g0 = gelu_pk(f32x2{bf_lo(hv.x), bf_hi(hv.x)} + f32x2{z0.x, z0.y});
        f32x2 g1 = gelu_pk(f32x2{bf_lo(hv.y), bf_hi(hv.y)} + f32x2{z0.z, z0.w});
        f32x2 g2 = gelu_pk(f32x2{bf_lo(hv.z), bf_hi(hv.z)} + f32x2{z1.x, z1.y});
        f32x2 g3 = gelu_pk(f32x2{bf_lo(hv.w), bf_hi(hv.w)} + f32x2{z1.z, z1.w});
        uint4 pk;
        pk.x = pack_bf16x2(g0.x, g0.y);
        pk.y = pack_bf16x2(g1.x, g1.y);
        pk.z = pack_bf16x2(g2.x, g2.y);
        pk.w = pack_bf16x2(g3.x, g3.y);
        *(uint4*)((char*)lA + (unsigned)(abuf * 8192) + awoff) = pk;
    };

    // ---- prologue ----
    HPSTAGE(0, 0);
    HPSTAGE(1, 1);
    lhz[t] = hz_part[b * 512 + t] + hz_part[65536 + b * 512 + t] + b1[t];
    __syncthreads();            // vmcnt drain: hstage0/1 + lhz ready
    AGEN(0, 0);
    __syncthreads();            // lA[0] ready

    // ---- main loop: one barrier per kt ----
    #pragma unroll 2
    for (int kt = 0; kt < 8; ++kt) {
        if (kt < 6) HPSTAGE(kt + 2, kt & 1);

        uint4 breg[2][4];
        #pragma unroll
        for (int kk = 0; kk < 2; ++kk)
            #pragma unroll
            for (int bf = 0; bf < 4; ++bf)
                breg[kk][bf] = *(const uint4*)
                    &W2F[(unsigned)(((kt * 2 + kk) * 32 + w * 4 + bf) * 512 + l * 8)];

        if (kt < 7) AGEN(kt + 1, (kt + 1) & 1);

        const char* abase = (const char*)lA + (kt & 1) * 8192;
        #pragma unroll
        for (int kk = 0; kk < 2; ++kk) {
            const int cch = kk * 4 + (l >> 4);
            bf16x8 af[4];
            #pragma unroll
            for (int a = 0; a < 4; ++a) {
                int row = 16 * a + (l & 15);
                unsigned off = (unsigned)(row * 128 + ((cch ^ (row & 7)) << 4));
                af[a] = __builtin_bit_cast(bf16x8, *(const uint4*)(abase + off));
            }
            #pragma unroll
            for (int bf = 0; bf < 4; ++bf) {
                bf16x8 bfr = __builtin_bit_cast(bf16x8, breg[kk][bf]);
                #pragma unroll
                for (int a = 0; a < 4; ++a)
                    acc[a][bf] = __builtin_amdgcn_mfma_f32_16x16x32_bf16(
                        af[a], bfr, acc[a][bf], 0, 0, 0);
            }
        }

        __syncthreads();
    }

    // ---- epilogue: +b2, gelu2 (packed), dot W3, reduce ----
    float b2v[4], w3v[4];
    #pragma unroll
    for (int bf = 0; bf < 4; ++bf) {
        int n = w * 64 + 16 * bf + (l & 15);
        b2v[bf] = b2[n];
        w3v[bf] = W3[n];
    }
    f32x2 ps[4][2];
    #pragma unroll
    for (int a = 0; a < 4; ++a) {
        ps[a][0] = f32x2{0.f, 0.f};
        ps[a][1] = f32x2{0.f, 0.f};
    }

    #pragma unroll
    for (int bf = 0; bf < 4; ++bf) {
        const f32x2 b2p = {b2v[bf], b2v[bf]};
        const f32x2 w3p = {w3v[bf], w3v[bf]};
        #pragma unroll
        for (int a = 0; a < 4; ++a) {
            f32x2 xlo = f32x2{acc[a][bf][0], acc[a][bf][1]} + b2p;
            f32x2 xhi = f32x2{acc[a][bf][2], acc[a][bf][3]} + b2p;
            ps[a][0] = __builtin_elementwise_fma(gelu_pk(xlo), w3p, ps[a][0]);
            ps[a][1] = __builtin_elementwise_fma(gelu_pk(xhi), w3p, ps[a][1]);
        }
    }

    float psum[4][4];
    #pragma unroll
    for (int a = 0; a < 4; ++a) {
        psum[a][0] = ps[a][0].x; psum[a][1] = ps[a][0].y;
        psum[a][2] = ps[a][1].x; psum[a][3] = ps[a][1].y;
    }

    #pragma unroll
    for (int a = 0; a < 4; ++a)
        #pragma unroll
        for (int r = 0; r < 4; ++r) {
            float v = psum[a][r];
            v += __shfl_xor(v, 1);
            v += __shfl_xor(v, 2);
            v += __shfl_xor(v, 4);
            v += __shfl_xor(v, 8);
            psum[a][r] = v;
        }

    if ((l & 15) == 0) {
        int gb = (l >> 4) * 4;
        #pragma unroll
        for (int a = 0; a < 4; ++a)
            #pragma unroll
            for (int r = 0; r < 4; ++r)
                lred[w][16 * a + gb + r] = psum[a][r];
    }
    __syncthreads();
    if (t < 64) {
        float s = b3[0];
        #pragma unroll
        for (int ww = 0; ww < 8; ++ww) s += lred[ww][t];
        out[r0 + t] = s;
    }
}

extern "C" void kernel_launch(void* const* d_in, const int* in_sizes, int n_in,
                              void* d_out, int out_size, void* d_ws, size_t ws_size,
                              hipStream_t stream) {
    (void)in_sizes; (void)n_in; (void)out_size; (void)ws_size;
    const float* g_q = (const float*)d_in[0];
    const float* Phi = (const float*)d_in[1];
    const float* W1  = (const float*)d_in[2];
    const float* b1  = (const float*)d_in[3];
    const float* W2  = (const float*)d_in[4];
    const float* b2  = (const float*)d_in[5];
    const float* W3  = (const float*)d_in[6];
    const float* b3  = (const float*)d_in[7];
    float* out = (float*)d_out;

    char* ws = (char*)d_ws;
    float*          hz_part = (float*)ws;                                // 512 KB
    unsigned short* hpb     = (unsigned short*)(ws + 524288);            // 1 MB
    unsigned short* W2F     = (unsigned short*)(ws + 1572864);           // 512 KB
    unsigned short* W1F     = (unsigned short*)(ws + 2097152);           // 1.5 MB

    hipLaunchKernelGGL(wcast_kernel, dim3(192), dim3(256), 0, stream,
                       W1, W1F);
    hipLaunchKernelGGL(l1w2_kernel, dim3(84), dim3(512), 0, stream,
                       g_q, Phi, W2, W1F, hz_part, hpb, W2F);
    hipLaunchKernelGGL(fused_kernel, dim3(2048), dim3(512), 0, stream,
                       hz_part, b1, hpb, W2F, b2, W3, b3, out);
}